// Round 1
// baseline (1475.033 us; speedup 1.0000x reference)
//
#include <hip/hip_runtime.h>
#include <math.h>

// Problem constants (from reference)
#define BB 256
#define TT_TOTAL 1024
#define DD 128
#define LL 16
#define OO 256
#define TILE 16          // timesteps per agg tile
#define DPAD (DD + 4)    // padded LDS row stride (floats); 132*4B = 528B, 16B-aligned

// One workgroup per batch element b. 512 threads:
//   o = tid>>1 (output column 0..255), h = tid&1 (which half of the i-range).
// Thread holds R[h*128 .. h*128+127][o] in 128 VGPRs.
// State s (256 fp32) double-buffered in LDS; per step each thread computes a
// half dot-product (128 FMA) from broadcast LDS reads, pair-combined via
// __shfl_xor(.,1). agg is computed cooperatively every TILE steps from x.
__global__ __launch_bounds__(512, 2)
void srkan_fused(const float* __restrict__ x,      // [B,T,D]
                 const float* __restrict__ subW,   // [L,D]
                 const float* __restrict__ subb,   // [L]
                 const float* __restrict__ aggW,   // [L,O]
                 const float* __restrict__ R,      // [O,O]
                 float* __restrict__ y)            // [B,T,O]
{
    const int b   = blockIdx.x;
    const int tid = threadIdx.x;
    const int o   = tid >> 1;
    const int h   = tid & 1;

    __shared__ float sW[LL][DPAD];      // sub_W, padded
    __shared__ float xs[TILE][DPAD];    // x tile, padded
    __shared__ float acts[TILE][LL];    // activations
    __shared__ float aggt[TILE][OO];    // agg tile
    __shared__ float sbuf[2][OO];       // double-buffered state
    __shared__ float bias[LL];

    // ---- one-time loads ----
    // sub_W: 2048 floats = 512 float4, one per thread (rows are 128 floats,
    // divisible by 4, so each float4 stays within a row)
    {
        const int idx = tid * 4;
        const int l = idx / DD, d = idx % DD;
        *(float4*)&sW[l][d] = *(const float4*)&subW[idx];
        if (tid < LL) bias[tid] = subb[tid];
        if (tid < OO) { sbuf[0][tid] = 0.f; sbuf[1][tid] = 0.f; }
    }

    // R half-column into registers: r[j] = R[h*128 + j][o]
    float r[128];
    {
        const float* Rp = R + (size_t)(h * 128) * OO + o;
#pragma unroll
        for (int j = 0; j < 128; ++j) r[j] = Rp[(size_t)j * OO];
    }
    // aggW column into registers
    float aW[LL];
#pragma unroll
    for (int l = 0; l < LL; ++l) aW[l] = aggW[l * OO + o];

    __syncthreads();

    const float* xb = x + (size_t)b * TT_TOTAL * DD;
    float*       yb = y + (size_t)b * TT_TOTAL * OO;

    for (int t0 = 0; t0 < TT_TOTAL; t0 += TILE) {
        // ---- Phase 1: load x tile (TILE*DD = 2048 floats = 512 float4) ----
        {
            const int idx = tid * 4;
            const int tt = idx / DD, d = idx % DD;
            *(float4*)&xs[tt][d] = *(const float4*)&xb[(size_t)t0 * DD + idx];
        }
        __syncthreads();

        // ---- Phase 2: pre + activation. 256 dots of length 128; pair (h)
        //      splits the d-range. ----
        {
            const int dot = tid >> 1;       // 0..255
            const int tt  = dot >> 4;       // 0..15
            const int l   = dot & 15;       // 0..15
            const float4* xv = (const float4*)&xs[tt][h * 64];
            const float4* wv = (const float4*)&sW[l][h * 64];
            float p0 = 0.f, p1 = 0.f, p2 = 0.f, p3 = 0.f;
#pragma unroll
            for (int j = 0; j < 16; ++j) {
                float4 a = xv[j], w = wv[j];
                p0 += a.x * w.x; p1 += a.y * w.y;
                p2 += a.z * w.z; p3 += a.w * w.w;
            }
            float p = (p0 + p1) + (p2 + p3);
            p += __shfl_xor(p, 1);
            if (h == 0) {
                p += bias[l];
                float v;
                switch (l & 3) {
                    case 0: v = tanhf(p); break;
                    case 1: v = fmaxf(p, 0.f); break;
                    case 2: v = 1.f / (1.f + expf(-p)); break;
                    default: v = p; break;
                }
                acts[tt][l] = v;
            }
        }
        __syncthreads();

        // ---- Phase 3: agg tile. Thread (o,h) computes 8 timesteps. ----
        {
#pragma unroll
            for (int k = 0; k < 8; ++k) {
                const int tt = h * 8 + k;
                const float4* av = (const float4*)acts[tt];
                float4 a0 = av[0], a1 = av[1], a2 = av[2], a3 = av[3];
                float s0 = a0.x * aW[0] + a0.y * aW[1] + a0.z * aW[2]  + a0.w * aW[3];
                float s1 = a1.x * aW[4] + a1.y * aW[5] + a1.z * aW[6]  + a1.w * aW[7];
                float s2 = a2.x * aW[8] + a2.y * aW[9] + a2.z * aW[10] + a2.w * aW[11];
                float s3 = a3.x * aW[12]+ a3.y * aW[13]+ a3.z * aW[14] + a3.w * aW[15];
                aggt[tt][o] = (s0 + s1) + (s2 + s3);
            }
        }
        __syncthreads();

        // ---- Phase 4: TILE recurrence steps ----
#pragma unroll 1
        for (int k = 0; k < TILE; ++k) {
            const int t = t0 + k;
            const float* sc = sbuf[t & 1];
            float*       sn = sbuf[(t + 1) & 1];
            const float4* s4 = (const float4*)(sc + h * 128);
            float acc0 = 0.f, acc1 = 0.f, acc2 = 0.f, acc3 = 0.f;
#pragma unroll
            for (int j = 0; j < 32; ++j) {
                float4 sv = s4[j];
                acc0 += sv.x * r[4 * j + 0];
                acc1 += sv.y * r[4 * j + 1];
                acc2 += sv.z * r[4 * j + 2];
                acc3 += sv.w * r[4 * j + 3];
            }
            float acc = (acc0 + acc2) + (acc1 + acc3);
            acc += __shfl_xor(acc, 1);
            const float ns = aggt[k][o] + acc;
            if (h == 0) {
                sn[o] = ns;
                yb[(size_t)t * OO + o] = ns;
            }
            __syncthreads();
        }
    }
}

extern "C" void kernel_launch(void* const* d_in, const int* in_sizes, int n_in,
                              void* d_out, int out_size, void* d_ws, size_t ws_size,
                              hipStream_t stream) {
    const float* x    = (const float*)d_in[0];
    const float* subW = (const float*)d_in[1];
    const float* subb = (const float*)d_in[2];
    const float* aggW = (const float*)d_in[3];
    const float* R    = (const float*)d_in[4];
    float* y = (float*)d_out;

    srkan_fused<<<BB, 512, 0, stream>>>(x, subW, subb, aggW, R, y);
}

// Round 2
// 1082.184 us; speedup vs baseline: 1.3630x; 1.3630x over previous
//
#include <hip/hip_runtime.h>
#include <math.h>

// Problem constants
#define BB 256
#define TT 1024
#define DD 128
#define LL 16
#define OO 256
#define TILE 16
#define DPAD 132     // padded row stride for [16][128] tiles (16B-aligned, 528B)
#define CPAD 20      // state chunk: 16 floats padded to 20 (80B, 16B-aligned)

// One block per batch b. 1024 threads = 16 waves (4/SIMD).
// Wave w owns outputs o in [w*16, w*16+16).
// Lane = og*16+ic: og in [0,4) selects a group of 4 outputs, ic in [0,16)
// selects i-range [ic*16, ic*16+16). Each lane holds R[i0..i0+15][o0..o0+3]
// in 64 VGPRs (guaranteed to fit: launch_bounds cap = 128).
// Per step: lane reads 16 state floats (4x ds_read_b128 from padded chunk),
// does 64 FMA, reduces partials over ic via 5 shfl_xor stages; 16 writer
// lanes/wave add agg and store new state (LDS, double-buffered) + y.
__global__ __launch_bounds__(1024, 4)
void srkan_fused(const float* __restrict__ x,      // [B,T,D]
                 const float* __restrict__ subW,   // [L,D]
                 const float* __restrict__ subb,   // [L]
                 const float* __restrict__ aggW,   // [L,O]
                 const float* __restrict__ R,      // [O,O]
                 float* __restrict__ y)            // [B,T,O]
{
    const int b    = blockIdx.x;
    const int tid  = threadIdx.x;
    const int lane = tid & 63;
    const int w    = tid >> 6;     // wave 0..15
    const int og   = lane >> 4;    // 0..3
    const int ic   = lane & 15;    // 0..15

    __shared__ float sW[LL][DPAD];       // sub_W
    __shared__ float xs[TILE][DPAD];     // x tile
    __shared__ float acts[TILE][LL];     // activations
    __shared__ float aggt[TILE][OO];     // agg tile
    __shared__ float aggWt[OO][LL];      // aggW transposed [o][l]
    __shared__ float sbuf[2][16][CPAD];  // double-buffered state, padded chunks
    __shared__ float bias[LL];

    // ---- one-time init ----
    if (tid < 512) {                     // sub_W: 2048 floats as float4
        const int idx = tid * 4;
        const int l = idx >> 7, d = idx & 127;
        *(float4*)&sW[l][d] = *(const float4*)&subW[idx];
    }
    if (tid < LL) bias[tid] = subb[tid];
    {                                    // aggW transpose: 4096 floats
        const int idx = tid * 4;
        const int l = idx >> 8, o0 = idx & 255;
        float4 v = *(const float4*)&aggW[idx];
        aggWt[o0 + 0][l] = v.x; aggWt[o0 + 1][l] = v.y;
        aggWt[o0 + 2][l] = v.z; aggWt[o0 + 3][l] = v.w;
    }
    for (int i = tid; i < 2 * 16 * CPAD; i += 1024)   // zero state (incl pads)
        ((float*)sbuf)[i] = 0.f;

    // ---- R fragment: r[v][j] = R[ic*16+j][w*16+og*4+v] ----
    float r[4][16];
    {
        const int o0 = w * 16 + og * 4;
        const int i0 = ic * 16;
        const float* Rp = R + (size_t)i0 * OO + o0;
#pragma unroll
        for (int j = 0; j < 16; ++j) {
            float4 v = *(const float4*)(Rp + (size_t)j * OO);
            r[0][j] = v.x; r[1][j] = v.y; r[2][j] = v.z; r[3][j] = v.w;
        }
    }

    // writer bookkeeping: lanes ic<4 hold the final sum for o offset f(ic)
    const int f_ic   = 2 * (ic & 1) + ((ic >> 1) & 1);
    const bool writer = (ic < 4);
    const int o_w    = w * 16 + og * 4 + f_ic;

    __syncthreads();

    const float* xb = x + (size_t)b * TT * DD;
    float*       yb = y + (size_t)b * TT * OO;

    for (int t0 = 0; t0 < TT; t0 += TILE) {
        // ---- Phase 1: stage x tile (2048 floats; each thread one float2) ----
        {
            const int idx = tid * 2;
            const int tt = idx >> 7, d = idx & 127;
            *(float2*)&xs[tt][d] = *(const float2*)&xb[(size_t)t0 * DD + idx];
        }
        __syncthreads();

        // ---- Phase 2: pre + activation (256 dots of 128, 4 threads/dot) ----
        {
            const int dot = tid >> 2;      // 0..255
            const int q   = tid & 3;
            const int tt  = dot >> 4, l = dot & 15;
            const float4* xv = (const float4*)&xs[tt][q * 32];
            const float4* wv = (const float4*)&sW[l][q * 32];
            float p0 = 0.f, p1 = 0.f, p2 = 0.f, p3 = 0.f;
#pragma unroll
            for (int j = 0; j < 8; ++j) {
                float4 a = xv[j], v = wv[j];
                p0 += a.x * v.x; p1 += a.y * v.y;
                p2 += a.z * v.z; p3 += a.w * v.w;
            }
            float p = (p0 + p1) + (p2 + p3);
            p += __shfl_xor(p, 1);
            p += __shfl_xor(p, 2);
            if (q == 0) {
                p += bias[l];
                float v;
                switch (l & 3) {
                    case 0:  v = tanhf(p); break;
                    case 1:  v = fmaxf(p, 0.f); break;
                    case 2:  v = 1.f / (1.f + expf(-p)); break;
                    default: v = p; break;
                }
                acts[tt][l] = v;
            }
        }
        __syncthreads();

        // ---- Phase 3: agg tile (each thread 4 (tt,o) dots of length 16) ----
        {
            const int g = tid >> 8;        // 0..3
            const int o = tid & 255;
            const float4* aw = (const float4*)&aggWt[o][0];
            float4 w0 = aw[0], w1 = aw[1], w2 = aw[2], w3 = aw[3];
#pragma unroll
            for (int kk = 0; kk < 4; ++kk) {
                const int tt = g * 4 + kk;
                const float4* av = (const float4*)&acts[tt][0];
                float4 a0 = av[0], a1 = av[1], a2 = av[2], a3 = av[3];
                float s0 = a0.x * w0.x + a0.y * w0.y + a0.z * w0.z + a0.w * w0.w;
                float s1 = a1.x * w1.x + a1.y * w1.y + a1.z * w1.z + a1.w * w1.w;
                float s2 = a2.x * w2.x + a2.y * w2.y + a2.z * w2.z + a2.w * w2.w;
                float s3 = a3.x * w3.x + a3.y * w3.y + a3.z * w3.z + a3.w * w3.w;
                aggt[tt][o] = (s0 + s1) + (s2 + s3);
            }
        }
        __syncthreads();

        // ---- Phase 4: TILE recurrence steps ----
#pragma unroll 1
        for (int k = 0; k < TILE; ++k) {
            const int t   = t0 + k;
            const int cur = t & 1;
            // state chunk: 16 floats, 4x b128, 2-way-conflict-free padding
            const float4* s4 = (const float4*)&sbuf[cur][ic][0];
            float4 s0 = s4[0], s1 = s4[1], s2 = s4[2], s3 = s4[3];
            float p0 = 0.f, p1 = 0.f, p2 = 0.f, p3 = 0.f;
#pragma unroll
            for (int j = 0; j < 4; ++j) {
                float sj;
                sj = (&s0.x)[j];
                p0 += sj * r[0][j];      p1 += sj * r[1][j];
                p2 += sj * r[2][j];      p3 += sj * r[3][j];
            }
#pragma unroll
            for (int j = 0; j < 4; ++j) {
                float sj = (&s1.x)[j];
                p0 += sj * r[0][4 + j];  p1 += sj * r[1][4 + j];
                p2 += sj * r[2][4 + j];  p3 += sj * r[3][4 + j];
            }
#pragma unroll
            for (int j = 0; j < 4; ++j) {
                float sj = (&s2.x)[j];
                p0 += sj * r[0][8 + j];  p1 += sj * r[1][8 + j];
                p2 += sj * r[2][8 + j];  p3 += sj * r[3][8 + j];
            }
#pragma unroll
            for (int j = 0; j < 4; ++j) {
                float sj = (&s3.x)[j];
                p0 += sj * r[0][12 + j]; p1 += sj * r[1][12 + j];
                p2 += sj * r[2][12 + j]; p3 += sj * r[3][12 + j];
            }
            // reduce over ic (16 lanes): halving exchange, masks 1,2,4,8
            float q0, q1;
            {
                const bool e = (ic & 1) == 0;
                float a0 = e ? p0 : p2;
                float a1 = e ? p1 : p3;
                float b0 = e ? p2 : p0;
                float b1 = e ? p3 : p1;
                q0 = a0 + __shfl_xor(b0, 1);
                q1 = a1 + __shfl_xor(b1, 1);
            }
            float u;
            {
                const bool e = (ic & 2) == 0;
                float a = e ? q0 : q1;
                float c = e ? q1 : q0;
                u = a + __shfl_xor(c, 2);
            }
            u += __shfl_xor(u, 4);
            u += __shfl_xor(u, 8);
            if (writer) {
                const float ns = u + aggt[k][o_w];
                sbuf[1 - cur][w][o_w & 15] = ns;   // o_w>>4 == w
                yb[(size_t)t * OO + o_w] = ns;
            }
            __syncthreads();
        }
    }
}

extern "C" void kernel_launch(void* const* d_in, const int* in_sizes, int n_in,
                              void* d_out, int out_size, void* d_ws, size_t ws_size,
                              hipStream_t stream) {
    const float* x    = (const float*)d_in[0];
    const float* subW = (const float*)d_in[1];
    const float* subb = (const float*)d_in[2];
    const float* aggW = (const float*)d_in[3];
    const float* R    = (const float*)d_in[4];
    float* yp = (float*)d_out;

    srkan_fused<<<BB, 1024, 0, stream>>>(x, subW, subb, aggW, R, yp);
}